// Round 2
// baseline (1231.407 us; speedup 1.0000x reference)
//
#include <hip/hip_runtime.h>

// ---------------------------------------------------------------------------
// HebbianBlock: out(B,T,D) f32; chunked linear-attention style recurrence.
// Pipeline: cast->bf16 | vT = Ww@rk^T (GEMM) | scan(inter, W-state in AGPRs) |
//           intra (S*M@v) | y = out + alpha*(inter+intra)@Wr^T (GEMM)
// ---------------------------------------------------------------------------

typedef __attribute__((ext_vector_type(8))) short short8;
typedef __attribute__((ext_vector_type(4))) short short4v;
typedef __attribute__((ext_vector_type(4))) float f32x4;

#define B_ 4
#define T_ 8192
#define D_ 1024
#define C_ 64
#define NC_ 128

#define DEVI static __device__ __forceinline__

// transcendentals: use clang builtins (glibc math.h macro collision with
// __expf/__exp2f/__log2f spellings on this toolchain)
#define EXPF(x) __builtin_expf(x)
#define LOG2F(x) __builtin_log2f(x)
#define EXP2F(x) __builtin_exp2f(x)

DEVI unsigned short f2bf_u(float f) {
  unsigned int u = __float_as_uint(f);
  u += 0x7fffu + ((u >> 16) & 1u);   // round-to-nearest-even
  return (unsigned short)(u >> 16);
}
DEVI short f2bfs(float f) { return (short)f2bf_u(f); }
DEVI float bf2fs(short h) { return __uint_as_float(((unsigned int)(unsigned short)h) << 16); }

DEVI f32x4 mfma16(short8 a, short8 b, f32x4 c) {
  return __builtin_amdgcn_mfma_f32_16x16x32_bf16(a, b, c, 0, 0, 0);
}

// ---------------------------------------------------------------- cast f32->bf16
__global__ __launch_bounds__(256) void k_cast(const float* __restrict__ src,
                                              short* __restrict__ dst, int n8) {
  int i = blockIdx.x * 256 + threadIdx.x;
  if (i >= n8) return;
  const float4* s = (const float4*)src;
  float4 a = s[2 * i], b = s[2 * i + 1];
  short8 o;
  o[0] = f2bfs(a.x); o[1] = f2bfs(a.y); o[2] = f2bfs(a.z); o[3] = f2bfs(a.w);
  o[4] = f2bfs(b.x); o[5] = f2bfs(b.y); o[6] = f2bfs(b.z); o[7] = f2bfs(b.w);
  *((short8*)dst + i) = o;
}

// ---------------------------------------------------------------- vT = Ww @ rk^T
// M = D (Ww rows d), N = B*T (rk rows t), K = D.  Output vT[b][d][t] (bf16).
__global__ __launch_bounds__(256) void k_gemm_v(const short* __restrict__ Aw,
                                                const short* __restrict__ Bx,
                                                short* __restrict__ vT) {
  __shared__ short As[128][72];
  __shared__ short Bs[128][72];
  const int tid = threadIdx.x;
  const int lane = tid & 63, wv = tid >> 6;
  const int wm = (wv >> 1) * 64, wn = (wv & 1) * 64;
  const int l16 = lane & 15, q = lane >> 4;
  const int m0 = blockIdx.y * 128;
  const int n0 = blockIdx.x * 128;
  f32x4 acc[4][4];
  for (int a = 0; a < 4; ++a)
    for (int b = 0; b < 4; ++b) acc[a][b] = (f32x4){0.f, 0.f, 0.f, 0.f};
  const int lrow = tid >> 3, lseg = tid & 7;
  const short* Ap = Aw + (size_t)(m0 + lrow) * D_ + lseg * 8;
  const short* Bp = Bx + (size_t)(n0 + lrow) * D_ + lseg * 8;
  for (int kb = 0; kb < D_; kb += 64) {
#pragma unroll
    for (int p = 0; p < 4; ++p) {
      *(short8*)&As[lrow + p * 32][lseg * 8] = *(const short8*)(Ap + (size_t)(p * 32) * D_ + kb);
      *(short8*)&Bs[lrow + p * 32][lseg * 8] = *(const short8*)(Bp + (size_t)(p * 32) * D_ + kb);
    }
    __syncthreads();
#pragma unroll
    for (int ks = 0; ks < 2; ++ks) {
      short8 af[4], bfr[4];
#pragma unroll
      for (int mt = 0; mt < 4; ++mt) af[mt] = *(const short8*)&As[wm + mt * 16 + l16][ks * 32 + q * 8];
#pragma unroll
      for (int nt = 0; nt < 4; ++nt) bfr[nt] = *(const short8*)&Bs[wn + nt * 16 + l16][ks * 32 + q * 8];
#pragma unroll
      for (int mt = 0; mt < 4; ++mt)
#pragma unroll
        for (int nt = 0; nt < 4; ++nt) acc[mt][nt] = mfma16(af[mt], bfr[nt], acc[mt][nt]);
    }
    __syncthreads();
  }
  const int b = n0 >> 13;                // T_ = 8192 rows per batch
  const int tbase = (n0 & (T_ - 1)) + wn;
  short* outp = vT + (size_t)b * D_ * T_;
#pragma unroll
  for (int mt = 0; mt < 4; ++mt)
#pragma unroll
    for (int nt = 0; nt < 4; ++nt)
#pragma unroll
      for (int i = 0; i < 4; ++i) {
        int d = m0 + wm + mt * 16 + q * 4 + i;
        int t = tbase + nt * 16 + l16;
        outp[(size_t)d * T_ + t] = f2bfs(acc[mt][nt][i]);
      }
}

// ---------------------------------------------------------------- scan (inter + W state)
// grid (64 d-tiles, 4 batches); block owns W[d0:d0+16][0:1024] in MFMA accs.
__global__ __launch_bounds__(256) void k_scan(const short* __restrict__ rk,
                                              const short* __restrict__ vT_g,
                                              short* __restrict__ inter_,
                                              const float* __restrict__ decay_p) {
  __shared__ short rs[2][65][264];   // rows t0-1..t0+63, one 256-wide e-tile, dbuf
  __shared__ short wT[256][64];      // transposed w tile, XOR-swizzled c-blocks
  __shared__ short vTs[16][72];      // v^T slice scaled by gw
  __shared__ short Wb[16][1032];     // bf16 copy of W slice (chunk-start value)
  const int tid = threadIdx.x;
  const int lane = tid & 63, wv = tid >> 6;
  const int l16 = lane & 15, q = lane >> 4;
  const int dt = blockIdx.x, b = blockIdx.y;
  const int d0 = dt * 16;
  const float gamma = 1.f / (1.f + EXPF(-decay_p[0]));
  const float lg2g = LOG2F(gamma);
  const float gC = EXP2F(64.f * lg2g);
  const short* rk_b = rk + (size_t)b * T_ * D_;
  const short* vT_b = vT_g + (size_t)b * D_ * T_ + (size_t)(d0 + (tid >> 4)) * T_ + (tid & 15) * 4;

  f32x4 Wacc[16];
#pragma unroll
  for (int j = 0; j < 16; ++j) Wacc[j] = (f32x4){0.f, 0.f, 0.f, 0.f};
  f32x4 iacc = (f32x4){0.f, 0.f, 0.f, 0.f};

  short8 pre[9];
  short4v vpre;

  auto load_tile = [&](int g1) {       // g1 = ch*4 + s
    int ch = g1 >> 2, s = g1 & 3;
    int e0 = s << 8;
    int tb = (ch << 6) - 1;
#pragma unroll
    for (int p = 0; p < 9; ++p) {
      int idx = p * 256 + tid;
      if (idx < 2080) {
        int row = idx >> 5, seg = idx & 31;
        int t = tb + row;
        if (t >= 0)
          pre[p] = *(const short8*)(rk_b + (size_t)t * D_ + e0 + seg * 8);
        else
          pre[p] = (short8){0, 0, 0, 0, 0, 0, 0, 0};
      }
    }
  };
  auto store_tile = [&](int buf) {
#pragma unroll
    for (int p = 0; p < 9; ++p) {
      int idx = p * 256 + tid;
      if (idx < 2080) {
        int row = idx >> 5, seg = idx & 31;
        *(short8*)&rs[buf][row][seg * 8] = pre[p];
      }
    }
  };

  // prime pipeline
  load_tile(0);
  vpre = *(const short4v*)(vT_b);
  store_tile(0);
  __syncthreads();

  const int c0t = (tid & 31) * 2;
  const int egt = tid >> 5;

  for (int ch = 0; ch < NC_; ++ch) {
    // (a) snapshot W into bf16 LDS (pre-update value), then scale accs by gamma^C
#pragma unroll
    for (int j = 0; j < 16; ++j) {
      int s = j >> 2, qq = j & 3;
      int e0 = (s << 8) + ((wv + (qq << 2)) << 4);
#pragma unroll
      for (int i = 0; i < 4; ++i) {
        Wb[q * 4 + i][e0 + l16] = f2bfs(Wacc[j][i]);
        Wacc[j][i] *= gC;
      }
    }
    for (int s = 0; s < 4; ++s) {
      const int g = (ch << 2) + s;
      const int cur = g & 1;
      // 1. prefetch next tile into regs (latency hidden by transpose+MFMA)
      if (g + 1 < 512) load_tile(g + 1);
      if (s == 3 && ch + 1 < NC_) vpre = *(const short4v*)(vT_b + ((ch + 1) << 6));
      // 2. LDS transpose: wT[e][c] = rs[c][e]  (w rows are rs rows 0..63)
#pragma unroll
      for (int pass = 0; pass < 4; ++pass) {
        int eb = pass * 64 + egt * 8;
        short8 r0 = *(const short8*)&rs[cur][c0t][eb];
        short8 r1 = *(const short8*)&rs[cur][c0t + 1][eb];
#pragma unroll
        for (int jj = 0; jj < 8; ++jj) {
          int e = eb + jj;
          int blk = (c0t >> 3) ^ (e & 7);
          unsigned int pk = ((unsigned int)(unsigned short)r1[jj] << 16) | (unsigned short)r0[jj];
          *(unsigned int*)&wT[e][blk * 8 + (c0t & 7)] = pk;
        }
      }
      if (s == 0) {   // stage v^T slice scaled by gw[c] = gamma^(63-c)
        int dd = tid >> 4, cs = (tid & 15) * 4;
#pragma unroll
        for (int jj = 0; jj < 4; ++jj) {
          int c = cs + jj;
          vTs[dd][c] = f2bfs(bf2fs(vpre[jj]) * EXP2F(lg2g * (float)(63 - c)));
        }
      }
      __syncthreads();   // A: wT/vTs/Wb ready
      // 4a. GEMM1: inter[c, d0:d0+16] partial over this e-tile
      {
        const int e0 = s << 8;
#pragma unroll
        for (int ks = 0; ks < 8; ++ks) {
          short8 af = *(const short8*)&rs[cur][wv * 16 + l16 + 1][ks * 32 + q * 8];
          short8 bfr = *(const short8*)&Wb[l16][e0 + ks * 32 + q * 8];
          iacc = mfma16(af, bfr, iacc);
        }
        // 4b. GEMM2: W += vg^T @ w for this wave's owned e-subtiles
#pragma unroll
        for (int qq = 0; qq < 4; ++qq) {
          int j = (s << 2) + qq;
          int el = (wv + (qq << 2)) << 4;
#pragma unroll
          for (int ks2 = 0; ks2 < 2; ++ks2) {
            int kk = ks2 * 32 + q * 8;
            short8 af = *(const short8*)&vTs[l16][kk];
            int e = el + l16;
            int blk2 = (kk >> 3) ^ (e & 7);
            short8 bfr = *(const short8*)&wT[e][blk2 * 8];
            Wacc[j] = mfma16(af, bfr, Wacc[j]);
          }
        }
      }
      // 5. write prefetched tile into other buffer
      if (g + 1 < 512) store_tile((g + 1) & 1);
      __syncthreads();   // B
    }
    // epilogue: inter rows scaled by gamma^c, stored bf16
    {
      const int t0 = ch << 6;
      size_t base = (size_t)b * T_ * D_ + d0 + l16;
#pragma unroll
      for (int i = 0; i < 4; ++i) {
        int c = wv * 16 + q * 4 + i;
        inter_[base + (size_t)(t0 + c) * D_] = f2bfs(iacc[i] * EXP2F(lg2g * (float)c));
        iacc[i] = 0.f;
      }
    }
  }
}

// ---------------------------------------------------------------- intra chunk
// grid (128 chunks, 4 batches): S = r@w^T (K=1024), P = S*M, intra = P@v
__global__ __launch_bounds__(256) void k_intra(const short* __restrict__ rk,
                                               const short* __restrict__ vT_g,
                                               short* __restrict__ intra_,
                                               const float* __restrict__ decay_p) {
  __shared__ short rs[65][264];
  __shared__ short P[64][72];
  __shared__ short vs[256][72];
  const int tid = threadIdx.x;
  const int lane = tid & 63, wv = tid >> 6;
  const int l16 = lane & 15, q = lane >> 4;
  const int ch = blockIdx.x, b = blockIdx.y;
  const int t0 = ch << 6;
  const float gamma = 1.f / (1.f + EXPF(-decay_p[0]));
  const float lg2g = LOG2F(gamma);
  const short* rk_b = rk + (size_t)b * T_ * D_;
  f32x4 Sacc[4];
#pragma unroll
  for (int j = 0; j < 4; ++j) Sacc[j] = (f32x4){0.f, 0.f, 0.f, 0.f};

  for (int s = 0; s < 4; ++s) {
    const int e0 = s << 8;
#pragma unroll
    for (int p = 0; p < 9; ++p) {
      int idx = p * 256 + tid;
      if (idx < 2080) {
        int row = idx >> 5, seg = idx & 31;
        int t = t0 - 1 + row;
        short8 v8;
        if (t >= 0) v8 = *(const short8*)(rk_b + (size_t)t * D_ + e0 + seg * 8);
        else v8 = (short8){0, 0, 0, 0, 0, 0, 0, 0};
        *(short8*)&rs[row][seg * 8] = v8;
      }
    }
    __syncthreads();
#pragma unroll
    for (int ks = 0; ks < 8; ++ks) {
      short8 af = *(const short8*)&rs[wv * 16 + l16 + 1][ks * 32 + q * 8];   // r rows
#pragma unroll
      for (int nt = 0; nt < 4; ++nt) {
        short8 bfr = *(const short8*)&rs[nt * 16 + l16][ks * 32 + q * 8];    // w rows
        Sacc[nt] = mfma16(af, bfr, Sacc[nt]);
      }
    }
    __syncthreads();
  }
  // mask: P[c][c'] = S * gamma^(c-1-c') for c>c', else 0
#pragma unroll
  for (int nt = 0; nt < 4; ++nt)
#pragma unroll
    for (int i = 0; i < 4; ++i) {
      int c = wv * 16 + q * 4 + i;
      int cp = nt * 16 + l16;
      float m = (c > cp) ? EXP2F(lg2g * (float)(c - 1 - cp)) : 0.f;
      P[c][cp] = f2bfs(Sacc[nt][i] * m);
    }
  __syncthreads();
  const short* vsrc = vT_g + (size_t)b * D_ * T_ + (size_t)tid * T_ + t0;
  size_t base = (size_t)b * T_ * D_;
  for (int p = 0; p < 4; ++p) {
    const short* sp = vsrc + (size_t)(p * 256) * T_;
#pragma unroll
    for (int seg = 0; seg < 8; ++seg)
      *(short8*)&vs[tid][seg * 8] = *(const short8*)(sp + seg * 8);
    __syncthreads();
    f32x4 acc[4][4];
#pragma unroll
    for (int a = 0; a < 4; ++a)
#pragma unroll
      for (int bb = 0; bb < 4; ++bb) acc[a][bb] = (f32x4){0.f, 0.f, 0.f, 0.f};
#pragma unroll
    for (int ks2 = 0; ks2 < 2; ++ks2) {
      short8 af[4];
#pragma unroll
      for (int mt = 0; mt < 4; ++mt) af[mt] = *(const short8*)&P[mt * 16 + l16][ks2 * 32 + q * 8];
#pragma unroll
      for (int nt = 0; nt < 4; ++nt) {
        short8 bfr = *(const short8*)&vs[wv * 64 + nt * 16 + l16][ks2 * 32 + q * 8];
#pragma unroll
        for (int mt = 0; mt < 4; ++mt) acc[mt][nt] = mfma16(af[mt], bfr, acc[mt][nt]);
      }
    }
#pragma unroll
    for (int mt = 0; mt < 4; ++mt)
#pragma unroll
      for (int nt = 0; nt < 4; ++nt)
#pragma unroll
        for (int i = 0; i < 4; ++i) {
          int c = mt * 16 + q * 4 + i;
          int d = p * 256 + wv * 64 + nt * 16 + l16;
          intra_[base + (size_t)(t0 + c) * D_ + d] = f2bfs(acc[mt][nt][i]);
        }
    __syncthreads();
  }
}

// ---------------------------------------------------------------- final GEMM
// y = out + alpha * (inter+intra) @ Wr^T.  M = B*T, N = D, K = D.
__global__ __launch_bounds__(256) void k_gemm_final(const short* __restrict__ inter_,
                                                    const short* __restrict__ intra_,
                                                    const short* __restrict__ Wr,
                                                    const float* __restrict__ xin,
                                                    float* __restrict__ y,
                                                    const float* __restrict__ la_p) {
  __shared__ short As[128][72];
  __shared__ short Bs[128][72];
  const float alpha = EXPF(la_p[0]);
  const int tid = threadIdx.x;
  const int lane = tid & 63, wv = tid >> 6;
  const int wm = (wv >> 1) * 64, wn = (wv & 1) * 64;
  const int l16 = lane & 15, q = lane >> 4;
  const int m0 = blockIdx.x * 128;
  const int n0 = blockIdx.y * 128;
  f32x4 acc[4][4];
  for (int a = 0; a < 4; ++a)
    for (int b = 0; b < 4; ++b) acc[a][b] = (f32x4){0.f, 0.f, 0.f, 0.f};
  const int lrow = tid >> 3, lseg = tid & 7;
  for (int kb = 0; kb < D_; kb += 64) {
#pragma unroll
    for (int p = 0; p < 4; ++p) {
      size_t aoff = (size_t)(m0 + lrow + p * 32) * D_ + kb + lseg * 8;
      short8 xa = *(const short8*)(inter_ + aoff);
      short8 xb = *(const short8*)(intra_ + aoff);
      short8 xs;
#pragma unroll
      for (int j = 0; j < 8; ++j) xs[j] = f2bfs(bf2fs(xa[j]) + bf2fs(xb[j]));
      *(short8*)&As[lrow + p * 32][lseg * 8] = xs;
      *(short8*)&Bs[lrow + p * 32][lseg * 8] =
          *(const short8*)(Wr + (size_t)(n0 + lrow + p * 32) * D_ + kb + lseg * 8);
    }
    __syncthreads();
#pragma unroll
    for (int ks = 0; ks < 2; ++ks) {
      short8 af[4], bfr[4];
#pragma unroll
      for (int mt = 0; mt < 4; ++mt) af[mt] = *(const short8*)&As[wm + mt * 16 + l16][ks * 32 + q * 8];
#pragma unroll
      for (int nt = 0; nt < 4; ++nt) bfr[nt] = *(const short8*)&Bs[wn + nt * 16 + l16][ks * 32 + q * 8];
#pragma unroll
      for (int mt = 0; mt < 4; ++mt)
#pragma unroll
        for (int nt = 0; nt < 4; ++nt) acc[mt][nt] = mfma16(af[mt], bfr[nt], acc[mt][nt]);
    }
    __syncthreads();
  }
#pragma unroll
  for (int mt = 0; mt < 4; ++mt)
#pragma unroll
    for (int nt = 0; nt < 4; ++nt)
#pragma unroll
      for (int i = 0; i < 4; ++i) {
        int t = m0 + wm + mt * 16 + q * 4 + i;
        int d = n0 + wn + nt * 16 + l16;
        size_t idx = (size_t)t * D_ + d;
        y[idx] = xin[idx] + alpha * acc[mt][nt][i];
      }
}

// ---------------------------------------------------------------- launch
extern "C" void kernel_launch(void* const* d_in, const int* in_sizes, int n_in,
                              void* d_out, int out_size, void* d_ws, size_t ws_size,
                              hipStream_t stream) {
  const float* x = (const float*)d_in[0];
  const float* Ww = (const float*)d_in[1];
  const float* Wr = (const float*)d_in[2];
  const float* decay = (const float*)d_in[3];
  const float* log_alpha = (const float*)d_in[4];
  float* y = (float*)d_out;

  short* ws = (short*)d_ws;
  const size_t NTD = (size_t)B_ * T_ * D_;   // 33,554,432
  short* rk_bf = ws;
  short* vT_bf = rk_bf + NTD;
  short* inter_b = vT_bf + NTD;
  short* intra_b = inter_b + NTD;
  short* Ww_bf = intra_b + NTD;
  short* Wr_bf = Ww_bf + (size_t)D_ * D_;
  // total ws use: 4*NTD + 2*D*D shorts = 272,629,760 bytes

  k_cast<<<(int)(NTD / 8 / 256), 256, 0, stream>>>(x, rk_bf, (int)(NTD / 8));
  k_cast<<<512, 256, 0, stream>>>(Ww, Ww_bf, (D_ * D_) / 8);
  k_cast<<<512, 256, 0, stream>>>(Wr, Wr_bf, (D_ * D_) / 8);
  k_gemm_v<<<dim3(256, 8), 256, 0, stream>>>(Ww_bf, rk_bf, vT_bf);
  k_scan<<<dim3(64, 4), 256, 0, stream>>>(rk_bf, vT_bf, inter_b, decay);
  k_intra<<<dim3(128, 4), 256, 0, stream>>>(rk_bf, vT_bf, intra_b, decay);
  k_gemm_final<<<dim3(256, 8), 256, 0, stream>>>(inter_b, intra_b, Wr_bf, x, y, log_alpha);
}